// Round 1
// baseline (95.960 us; speedup 1.0000x reference)
//
#include <hip/hip_runtime.h>

#define TPB 256

static constexpr float INV_TWO_PI = 0.15915494309189533577f;

// v_sin_f32 computes sin(2*pi*x) -- input is in REVOLUTIONS (cdna4_isa.md §3).
// Our inputs are in [0,1] (uniform mask / first diff_round output), well inside
// the valid HW range, so no fract/range-reduction needed.
__device__ __forceinline__ float sin2pi(float x) {
#if __has_builtin(__builtin_amdgcn_sinf)
    return __builtin_amdgcn_sinf(x);
#else
    return __sinf(6.28318530717958647693f * x);
#endif
}

__device__ __forceinline__ float diff_round(float x) {
    return x - sin2pi(x) * INV_TWO_PI;
}

// One tile = one (b,n) area = 64 contiguous floats.
// 16 lanes * float4 cover one tile; a wave (64 lanes) covers 4 tiles;
// a 256-thread block covers 16 tiles per grid-stride iteration.
// All tile reductions are xor-butterflies within the 16-lane group
// (masks 1,2,4,8 never cross the group boundary).
__global__ __launch_bounds__(TPB) void area_var_partial(
    const float* __restrict__ img, const float* __restrict__ msk,
    float* __restrict__ partial, int ntiles) {
    const int tid  = threadIdx.x;
    const int wave = tid >> 6;      // 0..3
    const int lane = tid & 63;
    const int grp  = lane >> 4;     // which of the wave's 4 tiles
    const int j    = lane & 15;     // lane within tile (float4 each)

    float acc = 0.0f;               // group-uniform running sum of varr
    const int tiles_per_block = (TPB / 64) * 4;  // 16
    for (int tbase = blockIdx.x * tiles_per_block; tbase < ntiles;
         tbase += gridDim.x * tiles_per_block) {
        const int tile = tbase + wave * 4 + grp;
        float4 iv = make_float4(0.f, 0.f, 0.f, 0.f);
        float4 mv = make_float4(0.f, 0.f, 0.f, 0.f);
        if (tile < ntiles) {
            const size_t off = (size_t)tile * 64 + (size_t)j * 4;
            iv = *reinterpret_cast<const float4*>(img + off);  // 16B/lane, coalesced
            mv = *reinterpret_cast<const float4*>(msk + off);
        }
        float m0 = diff_round(diff_round(mv.x));
        float m1 = diff_round(diff_round(mv.y));
        float m2 = diff_round(diff_round(mv.z));
        float m3 = diff_round(diff_round(mv.w));
        float x0 = iv.x * m0, x1 = iv.y * m1, x2 = iv.z * m2, x3 = iv.w * m3;

        float sm = (m0 + m1) + (m2 + m3);
        float sx = (x0 + x1) + (x2 + x3);
        #pragma unroll
        for (int d = 1; d < 16; d <<= 1) {
            sm += __shfl_xor(sm, d, 64);
            sx += __shfl_xor(sx, d, 64);
        }
        const float inv_msum = 1.0f / (sm + 1e-8f);
        const float mean = sx * inv_msum;

        float d0 = (x0 - mean) * m0;
        float d1 = (x1 - mean) * m1;
        float d2 = (x2 - mean) * m2;
        float d3 = (x3 - mean) * m3;
        float sd = (d0 * d0 + d1 * d1) + (d2 * d2 + d3 * d3);
        #pragma unroll
        for (int d = 1; d < 16; d <<= 1) sd += __shfl_xor(sd, d, 64);

        acc += sd * inv_msum;       // varr for this tile (zero for padded tiles)
    }
    // acc is uniform within each 16-lane group; butterfly over masks 16,32
    // sums the 4 distinct group values -> wave total (uniform over wave).
    acc += __shfl_xor(acc, 16, 64);
    acc += __shfl_xor(acc, 32, 64);

    __shared__ float wsum[TPB / 64];
    if (lane == 0) wsum[wave] = acc;
    __syncthreads();
    if (tid == 0) partial[blockIdx.x] = (wsum[0] + wsum[1]) + (wsum[2] + wsum[3]);
}

__global__ __launch_bounds__(TPB) void final_reduce(
    const float* __restrict__ partial, float* __restrict__ out,
    int n, float inv_count) {
    float s = 0.f;
    for (int i = threadIdx.x; i < n; i += TPB) s += partial[i];
    #pragma unroll
    for (int d = 1; d < 64; d <<= 1) s += __shfl_xor(s, d, 64);
    __shared__ float wsum[TPB / 64];
    const int wave = threadIdx.x >> 6;
    const int lane = threadIdx.x & 63;
    if (lane == 0) wsum[wave] = s;
    __syncthreads();
    if (threadIdx.x == 0)
        out[0] = ((wsum[0] + wsum[1]) + (wsum[2] + wsum[3])) * inv_count;
}

extern "C" void kernel_launch(void* const* d_in, const int* in_sizes, int n_in,
                              void* d_out, int out_size, void* d_ws, size_t ws_size,
                              hipStream_t stream) {
    const float* img = (const float*)d_in[0];   // sv_area_image [B,N,P,Q] fp32
    const float* msk = (const float*)d_in[1];   // sv_area_mask  [B,N,P,Q] fp32
    float* out = (float*)d_out;                 // scalar fp32
    float* partial = (float*)d_ws;              // nblocks floats of scratch

    const int ntiles = in_sizes[0] / 64;        // B*N = 131072
    int nblocks = (ntiles + 15) / 16;
    if (nblocks > 2048) nblocks = 2048;         // 8 blocks/CU -> 32 waves/CU

    area_var_partial<<<nblocks, TPB, 0, stream>>>(img, msk, partial, ntiles);
    final_reduce<<<1, TPB, 0, stream>>>(partial, out, nblocks,
                                        1.0f / (float)ntiles);
}

// Round 3
// 94.770 us; speedup vs baseline: 1.0126x; 1.0126x over previous
//
#include <hip/hip_runtime.h>

#define TPB 256

// v_sin_f32 computes sin(2*pi*x) -- input in REVOLUTIONS (cdna4_isa.md §3).
// Inputs are in [0,1] (uniform mask / first diff_round output): no range
// reduction needed.
__device__ __forceinline__ float sin2pi(float x) {
    return __builtin_amdgcn_sinf(x);
}

// diff_round(x) = x - sin(2pi x)/(2pi), as one sin + one fma
__device__ __forceinline__ float diff_round(float x) {
    return __builtin_fmaf(sin2pi(x), -0.15915494309189533577f, x);
}

// One v_add_f32_dpp: v += dpp_move(v, CTRL). Pure VALU -- no LDS pipe, no
// shuffle address math. CTRL must be an ICE -> template parameter.
template <int CTRL>
__device__ __forceinline__ float dpp_add(float v) {
    int i = __float_as_int(v);
    int m = __builtin_amdgcn_update_dpp(i, i, CTRL, 0xF, 0xF, false);
    return v + __int_as_float(m);
}

// Sum across a 16-lane DPP row (our tile group): butterfly xor1, xor2 via
// quad_perm, then row_ror:4 / row_ror:8 (rotation by 4/8 within the 16-lane
// row sums the four quad totals into every lane). 4 VALU instructions total.
__device__ __forceinline__ float row_sum16(float s) {
    s = dpp_add<0xB1>(s);   // quad_perm [1,0,3,2]  == xor 1
    s = dpp_add<0x4E>(s);   // quad_perm [2,3,0,1]  == xor 2
    s = dpp_add<0x124>(s);  // row_ror:4
    s = dpp_add<0x128>(s);  // row_ror:8
    return s;
}

// One tile = one (b,n) area = 64 contiguous floats.
// 16 lanes (one DPP row) * float4 cover one tile; a wave covers 4 tiles; a
// 256-thread block covers 16 tiles per grid-stride iteration. Loads are
// 16 B/lane fully coalesced (1 KB/wave/instruction).
__global__ __launch_bounds__(TPB) void area_var_partial(
    const float* __restrict__ img, const float* __restrict__ msk,
    float* __restrict__ partial, int ntiles) {
    const int tid  = threadIdx.x;
    const int wave = tid >> 6;      // 0..3
    const int lane = tid & 63;
    const int grp  = lane >> 4;     // which of the wave's 4 tiles (DPP row)
    const int j    = lane & 15;     // lane within tile (one float4 each)

    float acc = 0.0f;               // row-uniform running sum of varr
    const int tiles_per_block = (TPB / 64) * 4;  // 16
    for (int tbase = blockIdx.x * tiles_per_block; tbase < ntiles;
         tbase += gridDim.x * tiles_per_block) {
        const int tile = tbase + wave * 4 + grp;
        float4 iv = make_float4(0.f, 0.f, 0.f, 0.f);
        float4 mv = make_float4(0.f, 0.f, 0.f, 0.f);
        if (tile < ntiles) {
            const size_t off = (size_t)tile * 64 + (size_t)j * 4;
            iv = *reinterpret_cast<const float4*>(img + off);
            mv = *reinterpret_cast<const float4*>(msk + off);
        }
        float m0 = diff_round(diff_round(mv.x));
        float m1 = diff_round(diff_round(mv.y));
        float m2 = diff_round(diff_round(mv.z));
        float m3 = diff_round(diff_round(mv.w));
        float x0 = iv.x * m0, x1 = iv.y * m1, x2 = iv.z * m2, x3 = iv.w * m3;

        float sm = row_sum16((m0 + m1) + (m2 + m3));
        float sx = row_sum16((x0 + x1) + (x2 + x3));
        // v_rcp_f32 (~1 ulp) instead of the ~10-op IEEE div sequence;
        // output threshold is 1.5e-2, sums are O(10) -- plenty accurate.
        const float inv_msum = __builtin_amdgcn_rcpf(sm + 1e-8f);
        const float mean = sx * inv_msum;

        float d0 = (x0 - mean) * m0;
        float d1 = (x1 - mean) * m1;
        float d2 = (x2 - mean) * m2;
        float d3 = (x3 - mean) * m3;
        float sd = row_sum16((d0 * d0 + d1 * d1) + (d2 * d2 + d3 * d3));

        acc += sd * inv_msum;       // varr for this tile (row-uniform)
    }
    // acc uniform within each 16-lane row; sum the 4 rows of the wave.
    acc += __shfl_xor(acc, 16, 64);
    acc += __shfl_xor(acc, 32, 64);

    __shared__ float wsum[TPB / 64];
    if (lane == 0) wsum[wave] = acc;
    __syncthreads();
    if (tid == 0) partial[blockIdx.x] = (wsum[0] + wsum[1]) + (wsum[2] + wsum[3]);
}

__global__ __launch_bounds__(TPB) void final_reduce(
    const float* __restrict__ partial, float* __restrict__ out,
    int n, float inv_count) {
    float s = 0.f;
    for (int i = threadIdx.x; i < n; i += TPB) s += partial[i];
    #pragma unroll
    for (int d = 1; d < 64; d <<= 1) s += __shfl_xor(s, d, 64);
    __shared__ float wsum[TPB / 64];
    const int wave = threadIdx.x >> 6;
    const int lane = threadIdx.x & 63;
    if (lane == 0) wsum[wave] = s;
    __syncthreads();
    if (threadIdx.x == 0)
        out[0] = ((wsum[0] + wsum[1]) + (wsum[2] + wsum[3])) * inv_count;
}

extern "C" void kernel_launch(void* const* d_in, const int* in_sizes, int n_in,
                              void* d_out, int out_size, void* d_ws, size_t ws_size,
                              hipStream_t stream) {
    const float* img = (const float*)d_in[0];   // sv_area_image [B,N,P,Q] fp32
    const float* msk = (const float*)d_in[1];   // sv_area_mask  [B,N,P,Q] fp32
    float* out = (float*)d_out;                 // scalar fp32
    float* partial = (float*)d_ws;              // nblocks floats of scratch

    const int ntiles = in_sizes[0] / 64;        // B*N = 131072
    int nblocks = (ntiles + 15) / 16;
    if (nblocks > 2048) nblocks = 2048;         // 8 blocks/CU -> 32 waves/CU

    area_var_partial<<<nblocks, TPB, 0, stream>>>(img, msk, partial, ntiles);
    final_reduce<<<1, TPB, 0, stream>>>(partial, out, nblocks,
                                        1.0f / (float)ntiles);
}